// Round 2
// baseline (300.166 us; speedup 1.0000x reference)
//
#include <hip/hip_runtime.h>
#include <hip/hip_cooperative_groups.h>

namespace cg = cooperative_groups;

// Ball query via 5x5x5 uniform grid + parallel counting sort + per-wave hit
// bitmap. B=4, N1=2048 queries, N2=8192 keys, K=64, r=0.1 (cell = 0.2 = 2r,
// so a query ball overlaps at most a 2x2x2 octant of cells).
//
// R2: ONE cooperative dispatch. R0's three kernels (hist -> scatter -> query,
// 68.2 us) are kept byte-identical as PHASES separated by grid.sync();
// this removes two launch+drain boundaries. (R1's lesson: fusing hist+scatter
// by redundant per-block rescans cost +8 us — per-dispatch overhead is only
// ~2-3 us, so never trade redundant work for a dispatch.)
//   phase 1: blocks 0..127  : per-256-key-sub-block LDS histogram -> hists.
//   phase 2: blocks 0..127  : redundant scan of 32 sub-hists (L2-hot) ->
//            cell starts + per-sub base, scatter keys into sorted[B][N2]
//            float4{x,y,z,idx}. Disjoint per-(sub,cell) ranges => race-free.
//   phase 3: all 1024 blocks: one wave per query, 2 queries sequentially
//            (g=0,1). 8192-bit wave-private LDS bitmap keyed by ORIGINAL key
//            index; extract first K set bits in order (exact key-order
//            output even when >K hits).
// Fallback: if cooperative launch is rejected, run the same three phases as
// separate kernels (the verified R0 path).

constexpr int   K    = 64;
constexpr float R2   = 0.01f;   // 0.1^2
constexpr int   B    = 4;
constexpr int   N1   = 2048;
constexpr int   N2   = 8192;
constexpr int   GC   = 5;                 // grid cells per dim
constexpr int   NCELL = GC * GC * GC;     // 125
constexpr float INVCELL = 5.0f;           // 1 / 0.2
constexpr int   SUBS       = 128;         // 256-key sub-blocks total (B*N2/256)
constexpr int   SUBS_PER_B = 32;          // per batch

constexpr int   COOP_BLOCKS = 1024;       // 4 blocks/CU on 256 CUs

// ---------------- workspace layout ----------------
// [0, 512KB)   : sorted float4 [B*N2]
// then         : cell_start [B*(NCELL+1)] ints
// then         : hists [SUBS*NCELL] ints
constexpr size_t SORTED_BYTES = (size_t)B * N2 * 16;
constexpr size_t CS_BYTES     = (size_t)B * (NCELL + 1) * 4;
constexpr size_t WS_NEEDED    = SORTED_BYTES + CS_BYTES + (size_t)SUBS * NCELL * 4;

__device__ __forceinline__ int cell_of(float v) {
    int c = (int)(v * INVCELL);
    return c < 0 ? 0 : (c > GC - 1 ? GC - 1 : c);
}

// ================= phase bodies (shared by coop + fallback) =================

__device__ __forceinline__ void hist_body(
    const float* __restrict__ key, int* __restrict__ hists,
    int k /*sub-block*/, int t /*thread*/, int* h /*LDS[NCELL]*/)
{
    if (t < NCELL) h[t] = 0;
    __syncthreads();
    const int p = k * 256 + t;           // global key id
    const float x = key[p * 3 + 0];
    const float y = key[p * 3 + 1];
    const float z = key[p * 3 + 2];
    const int cell = (cell_of(x) * GC + cell_of(y)) * GC + cell_of(z);
    atomicAdd(&h[cell], 1);
    __syncthreads();
    if (t < NCELL) hists[k * NCELL + t] = h[t];
}

__device__ __forceinline__ void scatter_body(
    const float* __restrict__ key, const int* __restrict__ hists,
    int* __restrict__ cell_start, float4* __restrict__ sorted,
    int k, int t, int* sbuf /*LDS[128]*/, int* cursor /*LDS[NCELL]*/)
{
    const int b = k >> 5;                // batch
    const int s = k & 31;                // sub index within batch

    // Thread t (< NCELL) owns cell t: accumulate this batch's 32 sub-hists,
    // capturing the prefix over sub-blocks before mine.
    int mybase = 0, total = 0;
    if (t < NCELL) {
        const int* hb = hists + (b * SUBS_PER_B) * NCELL + t;
        int acc = 0;
        #pragma unroll
        for (int s2 = 0; s2 < SUBS_PER_B; ++s2) {
            if (s2 == s) mybase = acc;
            acc += hb[s2 * NCELL];
        }
        total = acc;
    }

    // Inclusive Hillis-Steele scan of per-cell totals (threads 0-127 active,
    // barriers unconditional for the whole block).
    if (t < 128) sbuf[t] = (t < NCELL) ? total : 0;
    __syncthreads();
    for (int off = 1; off < 128; off <<= 1) {
        int v = 0;
        if (t < 128 && t >= off) v = sbuf[t - off];
        __syncthreads();
        if (t < 128) sbuf[t] += v;
        __syncthreads();
    }
    if (t < NCELL) {
        const int excl = sbuf[t] - total;          // exclusive cell start
        cursor[t] = excl + mybase;                 // my sub-block's base in cell t
        if (s == 0) {                              // one writer per batch
            cell_start[b * (NCELL + 1) + t + 1] = sbuf[t];
            if (t == 0) cell_start[b * (NCELL + 1)] = 0;
        }
    }
    __syncthreads();

    // Scatter my 256 keys. Within-cell order arbitrary (bitmap restores it).
    const int p = k * 256 + t;                     // global key id
    const float x = key[p * 3 + 0];
    const float y = key[p * 3 + 1];
    const float z = key[p * 3 + 2];
    const int cell = (cell_of(x) * GC + cell_of(y)) * GC + cell_of(z);
    const int pos  = atomicAdd(&cursor[cell], 1);  // LDS, block-local
    float4 v;
    v.x = x; v.y = y; v.z = z; v.w = __int_as_float(p & (N2 - 1));
    sorted[(size_t)b * N2 + pos] = v;
}

__device__ __forceinline__ void query_body(
    const float* __restrict__ query, const float4* __restrict__ sorted,
    const int* __restrict__ cell_start, int* __restrict__ out,
    int q, int lane, unsigned int* wbm /*LDS[256] wave-private*/)
{
    const int b = q >> 11;

    const float qx = query[q * 3 + 0];
    const float qy = query[q * 3 + 1];
    const float qz = query[q * 3 + 2];

    // Octant of cells the ball can touch (cell = 2r, so +/-1 on the near side).
    const float ux = qx * INVCELL, uy = qy * INVCELL, uz = qz * INVCELL;
    const int cx = cell_of(qx), cy = cell_of(qy), cz = cell_of(qz);
    const int nx = (ux - cx < 0.5f) ? cx - 1 : cx + 1;
    const int ny = (uy - cy < 0.5f) ? cy - 1 : cy + 1;
    const int nz = (uz - cz < 0.5f) ? cz - 1 : cz + 1;
    const int xlo = max(0, min(cx, nx)), xhi = min(GC - 1, max(cx, nx));
    const int ylo = max(0, min(cy, ny)), yhi = min(GC - 1, max(cy, ny));
    const int zlo = max(0, min(cz, nz)), zhi = min(GC - 1, max(cz, nz));

    uint4 zz; zz.x = zz.y = zz.z = zz.w = 0u;
    ((uint4*)wbm)[lane] = zz;               // clear bitmap (ds_write_b128)

    const int*    cs = cell_start + b * (NCELL + 1);
    const float4* sb = sorted + (size_t)b * N2;

    for (int xx = xlo; xx <= xhi; ++xx) {
        for (int yy = ylo; yy <= yhi; ++yy) {
            const int colz = (xx * GC + yy) * GC;
            const int s = cs[colz + zlo];
            const int e = cs[colz + zhi + 1];          // z-cells are contiguous
            for (int t0 = s; t0 < e; t0 += 64) {
                const int i = t0 + lane;
                const float4 kv = sb[min(i, e - 1)];
                const float dx = kv.x - qx;
                const float dy = kv.y - qy;
                const float dz = kv.z - qz;
                const bool within = (i < e) && (dx * dx + dy * dy + dz * dz < R2);
                if (within) {
                    const int id = __float_as_int(kv.w);
                    atomicOr(&wbm[id >> 5], 1u << (id & 31));
                }
            }
        }
    }

    // ---- extraction: lane owns original-index range [128*lane, 128*lane+128)
    const uint4 w = ((const uint4*)wbm)[lane];
    const int c = __popc(w.x) + __popc(w.y) + __popc(w.z) + __popc(w.w);

    // inclusive wave prefix sum of c
    int x = c;
    #pragma unroll
    for (int off = 1; off < 64; off <<= 1) {
        int y = __shfl_up(x, off);
        if (lane >= off) x += y;
    }
    const int base = x - c;
    const int cnt  = __shfl(x, 63);

    // first set bit overall (0 if none)
    int fs;
    if      (w.x) fs = __builtin_ctz(w.x);
    else if (w.y) fs = 32 + __builtin_ctz(w.y);
    else if (w.z) fs = 64 + __builtin_ctz(w.z);
    else if (w.w) fs = 96 + __builtin_ctz(w.w);
    else          fs = 0;
    int myfirst = c ? (lane << 7) + fs : 0x7fffffff;
    #pragma unroll
    for (int off = 32; off; off >>= 1)
        myfirst = min(myfirst, __shfl_xor(myfirst, off));
    const int firstIdx = (cnt == 0) ? 0 : myfirst;

    // emit set bits in order
    int* op = out + q * K;
    int slot = base;
    unsigned int wr[4] = {w.x, w.y, w.z, w.w};
    #pragma unroll
    for (int r = 0; r < 4; ++r) {
        unsigned int m = wr[r];
        const int bb = (lane << 7) + (r << 5);
        while (m) {
            const int bp = __builtin_ctz(m);
            m &= m - 1;
            if (slot < K) op[slot] = bb + bp;
            ++slot;
        }
    }

    // pad remaining slots with firstIdx
    const int kpad = cnt < K ? cnt : K;
    const int s2 = kpad + lane;
    if (s2 < K) op[s2] = firstIdx;
}

// ================= single cooperative kernel =================

__global__ __launch_bounds__(256, 4) void fused_coop_kernel(
    const float* __restrict__ query, const float* __restrict__ key,
    int* __restrict__ cell_start, float4* __restrict__ sorted,
    int* __restrict__ hists, int* __restrict__ out)
{
    __shared__ int h[NCELL];
    __shared__ int sbuf[128];
    __shared__ int cursor[NCELL];
    __shared__ unsigned int bm[4 * 256];    // 4 waves x 8192-bit bitmap

    cg::grid_group grid = cg::this_grid();
    const int blk  = blockIdx.x;
    const int t    = threadIdx.x;
    const int lane = t & 63;
    const int wv   = t >> 6;

    if (blk < SUBS) hist_body(key, hists, blk, t, h);
    grid.sync();

    if (blk < SUBS) scatter_body(key, hists, cell_start, sorted, blk, t, sbuf, cursor);
    grid.sync();

    unsigned int* wbm = bm + wv * 256;
    #pragma unroll
    for (int g = 0; g < 2; ++g) {
        const int q = (blk * 4 + wv) + g * (COOP_BLOCKS * 4);   // 0..8191
        query_body(query, sorted, cell_start, out, q, lane, wbm);
    }
}

// ================= fallback standalone kernels (verified R0 path) ==========

__global__ __launch_bounds__(256) void hist_kernel(
    const float* __restrict__ key, int* __restrict__ hists)
{
    __shared__ int h[NCELL];
    hist_body(key, hists, blockIdx.x, threadIdx.x, h);
}

__global__ __launch_bounds__(256) void scatter_kernel(
    const float* __restrict__ key, const int* __restrict__ hists,
    int* __restrict__ cell_start, float4* __restrict__ sorted)
{
    __shared__ int sbuf[128];
    __shared__ int cursor[NCELL];
    scatter_body(key, hists, cell_start, sorted, blockIdx.x, threadIdx.x, sbuf, cursor);
}

__global__ __launch_bounds__(256) void ballquery_grid_kernel(
    const float* __restrict__ query, const float4* __restrict__ sorted,
    const int* __restrict__ cell_start, int* __restrict__ out)
{
    __shared__ unsigned int bm[4 * 256];
    const int lane = threadIdx.x & 63;
    const int wv   = threadIdx.x >> 6;
    const int q    = blockIdx.x * 4 + wv;
    query_body(query, sorted, cell_start, out, q, lane, bm + wv * 256);
}

// ---------------- fallback (ws too small): brute force ----------------
__global__ __launch_bounds__(256) void ballquery_bruteforce_kernel(
    const float* __restrict__ query, const float* __restrict__ key,
    int* __restrict__ out)
{
    const int lane = threadIdx.x & 63;
    const int q = blockIdx.x * 4 + (threadIdx.x >> 6);
    const int b = q >> 11;
    const float qx = query[q * 3], qy = query[q * 3 + 1], qz = query[q * 3 + 2];
    const float* kb = key + (size_t)b * N2 * 3;
    int* op = out + (size_t)q * K;
    int count = 0, first = 0;
    bool have_first = false;
    const unsigned long long lane_mask_lt = (lane == 0) ? 0ull : (~0ull >> (64 - lane));
    for (int c = 0; c < N2 / 64; ++c) {
        if (count >= K) break;
        const int j = (c << 6) + lane;
        const float* kp = kb + j * 3;
        const float dx = kp[0] - qx, dy = kp[1] - qy, dz = kp[2] - qz;
        const bool within = dx * dx + dy * dy + dz * dz < R2;
        const unsigned long long mask = __ballot(within);
        if (mask) {
            if (!have_first) { first = (c << 6) + __builtin_ctzll(mask); have_first = true; }
            if (within) {
                const int slot = count + __popcll(mask & lane_mask_lt);
                if (slot < K) op[slot] = j;
            }
            count += __popcll(mask);
        }
    }
    const int cnt = count < K ? count : K;
    if (cnt + lane < K) op[cnt + lane] = first;
}

extern "C" void kernel_launch(void* const* d_in, const int* in_sizes, int n_in,
                              void* d_out, int out_size, void* d_ws, size_t ws_size,
                              hipStream_t stream) {
    const float* query = (const float*)d_in[0];   // B*N1*3 floats
    const float* key   = (const float*)d_in[1];   // B*N2*3 floats
    int* out = (int*)d_out;                       // B*N1*K int32

    if (ws_size < WS_NEEDED) {
        ballquery_bruteforce_kernel<<<(B * N1) / 4, 256, 0, stream>>>(query, key, out);
        return;
    }

    float4* sorted     = (float4*)d_ws;
    int*    cell_start = (int*)((char*)d_ws + SORTED_BYTES);
    int*    hists      = (int*)((char*)d_ws + SORTED_BYTES + CS_BYTES);

    void* args[] = {(void*)&query, (void*)&key, (void*)&cell_start,
                    (void*)&sorted, (void*)&hists, (void*)&out};
    hipError_t err = hipLaunchCooperativeKernel(
        (const void*)fused_coop_kernel, dim3(COOP_BLOCKS), dim3(256),
        args, 0, stream);

    if (err != hipSuccess) {
        // Verified 3-dispatch path (R0).
        hist_kernel<<<SUBS, 256, 0, stream>>>(key, hists);
        scatter_kernel<<<SUBS, 256, 0, stream>>>(key, hists, cell_start, sorted);
        ballquery_grid_kernel<<<(B * N1) / 4, 256, 0, stream>>>(query, sorted, cell_start, out);
    }
}

// Round 3
// 78.785 us; speedup vs baseline: 3.8099x; 3.8099x over previous
//
#include <hip/hip_runtime.h>

// Ball query via 5x5x5 uniform grid + parallel counting sort + per-wave hit
// bitmap. B=4, N1=2048 queries, N2=8192 keys, K=64, r=0.1 (cell = 0.2 = 2r,
// so a query ball overlaps at most a 2x2x2 octant of cells).
//
// R3: TWO dispatches. R0's verified hist/scatter phases are fused into one
// 128-block kernel via a flag handshake (NOT cg::grid.sync — R2 showed that
// primitive costs ~120 us/sync on this stack):
//   - each block computes its 256-key LDS histogram, stores it to hists[],
//     __threadfence(), then release-stores flags[k] = 0xA1B2C300|k.
//   - 32 lanes acquire-spin on the 32 flags of their batch, then the block
//     runs the scatter phase (reusing key coords/cell kept in registers from
//     the hist phase). Spin time = skew across 128 co-resident blocks doing
//     identical ~2us work (<<1us). Flags have 4 pairwise-distinct bytes, so
//     no repeating-byte poison fill can forge one.
//   - per-(sub,cell) output ranges are disjoint => race-free deterministic
//     scatter, no global atomics.
// Query kernel unchanged from R0 (verified): one wave per query, <=4
// contiguous (x,y)-column z-runs, 8192-bit wave-private LDS bitmap keyed by
// ORIGINAL key index, extract first K set bits in order (exact key-order
// output even when >K hits).
//
// Lessons encoded: R1 (fuse-by-redundancy, 1 wave/SIMD build): +8us. R2
// (cg::grid.sync): +232us. Dispatch boundary is only worth ~2-3us — never
// buy it with redundant work or heavyweight sync.

constexpr int   K    = 64;
constexpr float R2   = 0.01f;   // 0.1^2
constexpr int   B    = 4;
constexpr int   N1   = 2048;
constexpr int   N2   = 8192;
constexpr int   GC   = 5;                 // grid cells per dim
constexpr int   NCELL = GC * GC * GC;     // 125
constexpr float INVCELL = 5.0f;           // 1 / 0.2
constexpr int   SUBS       = 128;         // 256-key sub-blocks total (B*N2/256)
constexpr int   SUBS_PER_B = 32;          // per batch

constexpr unsigned FLAG_BASE = 0xA1B2C300u; // bytes A1,B2,C3,k — all distinct

// ---------------- workspace layout ----------------
// [0, 512KB)   : sorted float4 [B*N2]
// then         : cell_start [B*(NCELL+1)] ints
// then         : hists [SUBS*NCELL] ints
// then         : flags [SUBS] uints
constexpr size_t SORTED_BYTES = (size_t)B * N2 * 16;
constexpr size_t CS_BYTES     = (size_t)B * (NCELL + 1) * 4;
constexpr size_t HIST_BYTES   = (size_t)SUBS * NCELL * 4;
constexpr size_t WS_NEEDED    = SORTED_BYTES + CS_BYTES + HIST_BYTES + SUBS * 4;

__device__ __forceinline__ int cell_of(float v) {
    int c = (int)(v * INVCELL);
    return c < 0 ? 0 : (c > GC - 1 ? GC - 1 : c);
}

__device__ __forceinline__ unsigned agent_load_acq(const unsigned* p) {
    return __hip_atomic_load(p, __ATOMIC_ACQUIRE, __HIP_MEMORY_SCOPE_AGENT);
}
__device__ __forceinline__ void agent_store_rel(unsigned* p, unsigned v) {
    __hip_atomic_store(p, v, __ATOMIC_RELEASE, __HIP_MEMORY_SCOPE_AGENT);
}

// ================= pass 1: fused hist -> handshake -> scatter ==============

__global__ __launch_bounds__(256) void build_fused_kernel(
    const float* __restrict__ key,       // [B*N2, 3]
    int* __restrict__ hists,             // [SUBS, NCELL]
    unsigned* __restrict__ flags,        // [SUBS]
    int* __restrict__ cell_start,        // [B, NCELL+1]
    float4* __restrict__ sorted)         // [B*N2]
{
    __shared__ int h[NCELL];
    __shared__ int sbuf[128];
    __shared__ int cursor[NCELL];

    const int k = blockIdx.x;            // sub-block id 0..127
    const int b = k >> 5;                // batch
    const int s = k & 31;                // sub index within batch
    const int t = threadIdx.x;

    // ---- hist phase (verified R0 body) ----
    if (t < NCELL) h[t] = 0;
    __syncthreads();
    const int p = k * 256 + t;           // global key id
    const float x = key[p * 3 + 0];
    const float y = key[p * 3 + 1];
    const float z = key[p * 3 + 2];
    const int cell = (cell_of(x) * GC + cell_of(y)) * GC + cell_of(z);
    atomicAdd(&h[cell], 1);
    __syncthreads();
    if (t < NCELL) hists[k * NCELL + t] = h[t];

    // ---- handshake: publish my hist, wait for my batch's 32 hists ----
    __threadfence();                     // agent-scope: hist stores visible
    __syncthreads();                     // all writers fenced before release
    if (t == 0) agent_store_rel(&flags[k], FLAG_BASE | (unsigned)k);
    if (t < SUBS_PER_B) {
        const int src = b * SUBS_PER_B + t;
        const unsigned want = FLAG_BASE | (unsigned)src;
        while (agent_load_acq(&flags[src]) != want) { /* spin */ }
    }
    __syncthreads();

    // ---- scatter phase (verified R0 body; key coords reused from regs) ----
    int mybase = 0, total = 0;
    if (t < NCELL) {
        const int* hb = hists + (b * SUBS_PER_B) * NCELL + t;
        int acc = 0;
        #pragma unroll
        for (int s2 = 0; s2 < SUBS_PER_B; ++s2) {
            if (s2 == s) mybase = acc;
            acc += hb[s2 * NCELL];
        }
        total = acc;
    }

    // Inclusive Hillis-Steele scan of per-cell totals (threads 0-127 active,
    // barriers unconditional for the whole block).
    if (t < 128) sbuf[t] = (t < NCELL) ? total : 0;
    __syncthreads();
    for (int off = 1; off < 128; off <<= 1) {
        int v = 0;
        if (t < 128 && t >= off) v = sbuf[t - off];
        __syncthreads();
        if (t < 128) sbuf[t] += v;
        __syncthreads();
    }
    if (t < NCELL) {
        const int excl = sbuf[t] - total;          // exclusive cell start
        cursor[t] = excl + mybase;                 // my sub-block's base in cell t
        if (s == 0) {                              // one writer per batch
            cell_start[b * (NCELL + 1) + t + 1] = sbuf[t];
            if (t == 0) cell_start[b * (NCELL + 1)] = 0;
        }
    }
    __syncthreads();

    // Scatter my 256 keys. Within-cell order arbitrary (bitmap restores it).
    const int pos = atomicAdd(&cursor[cell], 1);   // LDS, block-local
    float4 v;
    v.x = x; v.y = y; v.z = z; v.w = __int_as_float(p & (N2 - 1));
    sorted[(size_t)b * N2 + pos] = v;
}

// ---------------- pass 2: per-query grid scan (verified R0 body) -----------

__global__ __launch_bounds__(256) void ballquery_grid_kernel(
    const float* __restrict__ query,        // [B*N1, 3]
    const float4* __restrict__ sorted,      // [B*N2] grouped by cell
    const int* __restrict__ cell_start,     // [B, 126]
    int* __restrict__ out)                  // [B*N1, K]
{
    __shared__ unsigned int bm[4 * 256];    // 4 waves x 8192-bit bitmap

    const int lane = threadIdx.x & 63;
    const int wv   = threadIdx.x >> 6;
    const int q    = blockIdx.x * 4 + wv;   // 0 .. B*N1-1
    const int b    = q >> 11;

    const float qx = query[q * 3 + 0];
    const float qy = query[q * 3 + 1];
    const float qz = query[q * 3 + 2];

    // Octant of cells the ball can touch (cell = 2r, so +/-1 on the near side).
    const float ux = qx * INVCELL, uy = qy * INVCELL, uz = qz * INVCELL;
    const int cx = cell_of(qx), cy = cell_of(qy), cz = cell_of(qz);
    const int nx = (ux - cx < 0.5f) ? cx - 1 : cx + 1;
    const int ny = (uy - cy < 0.5f) ? cy - 1 : cy + 1;
    const int nz = (uz - cz < 0.5f) ? cz - 1 : cz + 1;
    const int xlo = max(0, min(cx, nx)), xhi = min(GC - 1, max(cx, nx));
    const int ylo = max(0, min(cy, ny)), yhi = min(GC - 1, max(cy, ny));
    const int zlo = max(0, min(cz, nz)), zhi = min(GC - 1, max(cz, nz));

    unsigned int* wbm = bm + wv * 256;
    uint4 zz; zz.x = zz.y = zz.z = zz.w = 0u;
    ((uint4*)wbm)[lane] = zz;               // clear bitmap (ds_write_b128)

    const int*    cs = cell_start + b * (NCELL + 1);
    const float4* sb = sorted + (size_t)b * N2;

    for (int xx = xlo; xx <= xhi; ++xx) {
        for (int yy = ylo; yy <= yhi; ++yy) {
            const int colz = (xx * GC + yy) * GC;
            const int s = cs[colz + zlo];
            const int e = cs[colz + zhi + 1];          // z-cells are contiguous
            for (int t0 = s; t0 < e; t0 += 64) {
                const int i = t0 + lane;
                const float4 kv = sb[min(i, e - 1)];
                const float dx = kv.x - qx;
                const float dy = kv.y - qy;
                const float dz = kv.z - qz;
                const bool within = (i < e) && (dx * dx + dy * dy + dz * dz < R2);
                if (within) {
                    const int id = __float_as_int(kv.w);
                    atomicOr(&wbm[id >> 5], 1u << (id & 31));
                }
            }
        }
    }

    // ---- extraction: lane owns original-index range [128*lane, 128*lane+128)
    const uint4 w = ((const uint4*)wbm)[lane];
    const int c = __popc(w.x) + __popc(w.y) + __popc(w.z) + __popc(w.w);

    // inclusive wave prefix sum of c
    int x = c;
    #pragma unroll
    for (int off = 1; off < 64; off <<= 1) {
        int y = __shfl_up(x, off);
        if (lane >= off) x += y;
    }
    const int base = x - c;
    const int cnt  = __shfl(x, 63);

    // first set bit overall (0 if none)
    int fs;
    if      (w.x) fs = __builtin_ctz(w.x);
    else if (w.y) fs = 32 + __builtin_ctz(w.y);
    else if (w.z) fs = 64 + __builtin_ctz(w.z);
    else if (w.w) fs = 96 + __builtin_ctz(w.w);
    else          fs = 0;
    int myfirst = c ? (lane << 7) + fs : 0x7fffffff;
    #pragma unroll
    for (int off = 32; off; off >>= 1)
        myfirst = min(myfirst, __shfl_xor(myfirst, off));
    const int firstIdx = (cnt == 0) ? 0 : myfirst;

    // emit set bits in order
    int* op = out + q * K;
    int slot = base;
    unsigned int wr[4] = {w.x, w.y, w.z, w.w};
    #pragma unroll
    for (int r = 0; r < 4; ++r) {
        unsigned int m = wr[r];
        const int bb = (lane << 7) + (r << 5);
        while (m) {
            const int bp = __builtin_ctz(m);
            m &= m - 1;
            if (slot < K) op[slot] = bb + bp;
            ++slot;
        }
    }

    // pad remaining slots with firstIdx
    const int kpad = cnt < K ? cnt : K;
    const int s2 = kpad + lane;
    if (s2 < K) op[s2] = firstIdx;
}

// ---------------- fallback (ws too small): brute force ----------------
__global__ __launch_bounds__(256) void ballquery_bruteforce_kernel(
    const float* __restrict__ query, const float* __restrict__ key,
    int* __restrict__ out)
{
    const int lane = threadIdx.x & 63;
    const int q = blockIdx.x * 4 + (threadIdx.x >> 6);
    const int b = q >> 11;
    const float qx = query[q * 3], qy = query[q * 3 + 1], qz = query[q * 3 + 2];
    const float* kb = key + (size_t)b * N2 * 3;
    int* op = out + (size_t)q * K;
    int count = 0, first = 0;
    bool have_first = false;
    const unsigned long long lane_mask_lt = (lane == 0) ? 0ull : (~0ull >> (64 - lane));
    for (int c = 0; c < N2 / 64; ++c) {
        if (count >= K) break;
        const int j = (c << 6) + lane;
        const float* kp = kb + j * 3;
        const float dx = kp[0] - qx, dy = kp[1] - qy, dz = kp[2] - qz;
        const bool within = dx * dx + dy * dy + dz * dz < R2;
        const unsigned long long mask = __ballot(within);
        if (mask) {
            if (!have_first) { first = (c << 6) + __builtin_ctzll(mask); have_first = true; }
            if (within) {
                const int slot = count + __popcll(mask & lane_mask_lt);
                if (slot < K) op[slot] = j;
            }
            count += __popcll(mask);
        }
    }
    const int cnt = count < K ? count : K;
    if (cnt + lane < K) op[cnt + lane] = first;
}

extern "C" void kernel_launch(void* const* d_in, const int* in_sizes, int n_in,
                              void* d_out, int out_size, void* d_ws, size_t ws_size,
                              hipStream_t stream) {
    const float* query = (const float*)d_in[0];   // B*N1*3 floats
    const float* key   = (const float*)d_in[1];   // B*N2*3 floats
    int* out = (int*)d_out;                       // B*N1*K int32

    if (ws_size < WS_NEEDED) {
        ballquery_bruteforce_kernel<<<(B * N1) / 4, 256, 0, stream>>>(query, key, out);
        return;
    }

    float4*   sorted     = (float4*)d_ws;
    int*      cell_start = (int*)((char*)d_ws + SORTED_BYTES);
    int*      hists      = (int*)((char*)d_ws + SORTED_BYTES + CS_BYTES);
    unsigned* flags      = (unsigned*)((char*)d_ws + SORTED_BYTES + CS_BYTES + HIST_BYTES);

    build_fused_kernel<<<SUBS, 256, 0, stream>>>(key, hists, flags, cell_start, sorted);
    ballquery_grid_kernel<<<(B * N1) / 4, 256, 0, stream>>>(query, sorted, cell_start, out);
}